// Round 5
// baseline (535.738 us; speedup 1.0000x reference)
//
#include <hip/hip_runtime.h>
#include <stdint.h>

// GraphTransformerLayer MI355X: B=32 T=128 N=42 E=256 H=8 DH=32, f32 I/O.
// Round 5: S^T orientation (lane-local softmax), wave-private transposes
// (barriers 6->4), 3-pass QKV, hw cvt_pk bf16 conversions.

#define TPB 512
constexpr int BT = 4096;
constexpr int N = 42, NP = 48, E = 256, H = 8;
constexpr int NE = N * E;          // 10752
constexpr int NN = N * N;          // 1764
constexpr float SCALE = 0.17677669529663687f;  // 1/sqrt(32)

typedef short sh8 __attribute__((ext_vector_type(8)));   // 8 bf16
typedef float f4 __attribute__((ext_vector_type(4)));    // MFMA C/D frag

__device__ __forceinline__ uint32_t cvtpk(float lo, float hi) {
  uint32_t d;
  asm("v_cvt_pk_bf16_f32 %0, %1, %2" : "=v"(d) : "v"(lo), "v"(hi));
  return d;
}
__device__ __forceinline__ uint16_t f2b1(float f) { return (uint16_t)cvtpk(f, f); }
__device__ __forceinline__ float b2f(uint16_t u) {
  union { uint32_t i; float f; } v; v.i = ((uint32_t)u) << 16; return v.f;
}

// XOR swizzle for row-major bf16 [*][256] LDS tiles (512B row stride).
#define SWZ(base, row, cb) \
  ((char*)(base) + ((((row) << 9) + (cb)) ^ (((row) & 7) << 4)))

// ---- pre-pass: WT[n][k] = bf16(W[k][n]), 4 matrices -------------------------
__global__ __launch_bounds__(256) void wt_kernel(
    const float* __restrict__ Wq, const float* __restrict__ Wk,
    const float* __restrict__ Wv, const float* __restrict__ Wo,
    uint16_t* __restrict__ WT) {
  __shared__ float tl[32][33];
  const int z = blockIdx.z;
  const float* W = (z == 0) ? Wq : (z == 1) ? Wk : (z == 2) ? Wv : Wo;
  uint16_t* dst = WT + z * 65536;
  const int k0 = blockIdx.y * 32, n0 = blockIdx.x * 32;
  const int r = threadIdx.x >> 5, cc = threadIdx.x & 31;
#pragma unroll
  for (int p = 0; p < 4; ++p)
    tl[r + 8 * p][cc] = W[(k0 + r + 8 * p) * E + n0 + cc];
  __syncthreads();
#pragma unroll
  for (int p = 0; p < 4; ++p)
    dst[(n0 + r + 8 * p) * E + k0 + cc] = f2b1(tl[cc][r + 8 * p]);
}

// one QKV/Wo GEMM pass: acc[mt][nt] += Xb(swz) @ Wt^T tiles, 24 live acc regs
__device__ __forceinline__ void gemm_pass(const uint16_t* __restrict__ Wt,
                                          const char* Xb, int c, int lg, int nt0,
                                          f4 acc[3][2]) {
#pragma unroll
  for (int mt = 0; mt < 3; ++mt)
#pragma unroll
    for (int nt = 0; nt < 2; ++nt) acc[mt][nt] = (f4){0.f, 0.f, 0.f, 0.f};
  for (int kc = 0; kc < E; kc += 32) {
    sh8 xa[3];
#pragma unroll
    for (int mt = 0; mt < 3; ++mt)
      xa[mt] = *(const sh8*)SWZ(Xb, 16 * mt + c, (kc + 8 * lg) * 2);
#pragma unroll
    for (int nt = 0; nt < 2; ++nt) {
      const sh8 b8 = *(const sh8*)(Wt + ((nt0 + nt) * 16 + c) * E + kc + 8 * lg);
#pragma unroll
      for (int mt = 0; mt < 3; ++mt)
        acc[mt][nt] = __builtin_amdgcn_mfma_f32_16x16x32_bf16(xa[mt], b8, acc[mt][nt], 0, 0, 0);
    }
  }
}

// wave-private C-frag -> row-major [48][40] scratch -> A/B frags (lane = row)
__device__ __forceinline__ void tr_qk(const f4 acc[3][2], const float* __restrict__ bias,
                                      int n0, int c, int lg, uint16_t* scr, sh8 fr[3]) {
#pragma unroll
  for (int nt = 0; nt < 2; ++nt) {
    const float bv = bias[n0 + 16 * nt + c];
#pragma unroll
    for (int mt = 0; mt < 3; ++mt)
#pragma unroll
      for (int r = 0; r < 4; ++r)
        scr[(16 * mt + 4 * lg + r) * 40 + 16 * nt + c] = f2b1(acc[mt][nt][r] + bv);
  }
#pragma unroll
  for (int mt = 0; mt < 3; ++mt)
    fr[mt] = *(const sh8*)(scr + (16 * mt + c) * 40 + 8 * lg);
}

// ---- main fused kernel ------------------------------------------------------
// LDS (70368 B -> 2 blocks/CU):
//  [0,24576)      Xb swz [48][256] -> VT [256][48] -> O swz [48][256]
//  [24576,67584)  per-wave 5376B: QK-tr [48][40] -> Ps [48][56]
//  [67584,69888)  dm8 [48][48];  [69888,70368) relL[120]
__global__ __launch_bounds__(TPB, 4) void gt_kernel(
    const float* __restrict__ X, const float* __restrict__ adj,
    const int* __restrict__ dist,
    const float* __restrict__ bq, const float* __restrict__ bk,
    const float* __restrict__ bv, const float* __restrict__ bo,
    const float* __restrict__ rel, const uint16_t* __restrict__ WT,
    float* __restrict__ out, float* __restrict__ attn) {
  alignas(16) __shared__ char smem[70368];
  char* const Xb = smem;
  uint16_t* const VT = (uint16_t*)smem;                 // [256][48]
  uint8_t*  const dm8 = (uint8_t*)(smem + 67584);
  float*    const relL = (float*)(smem + 69888);

  const int gid = blockIdx.x;
  const int tid = threadIdx.x;
  const int w = tid >> 6, lane = tid & 63, c = lane & 15, lg = lane >> 4;
  const int nt0 = 2 * w, n0 = 32 * w;
  uint16_t* const scr = (uint16_t*)(smem + 24576 + w * 5376);  // wave-private

  // ---- P1: stage X (f32->bf16, swizzled) + pad rows + dm8 + rel ------------
  {
    const float4* Xs = (const float4*)(X + (size_t)gid * NE);
    for (int i = tid; i < NE / 4; i += TPB) {
      const float4 v = Xs[i];
      uint2 pk; pk.x = cvtpk(v.x, v.y); pk.y = cvtpk(v.z, v.w);
      *(uint2*)SWZ(Xb, i >> 6, (i & 63) << 3) = pk;
    }
    for (int i = tid; i < (NP - N) * 32; i += TPB) {
      uint2 z; z.x = 0u; z.y = 0u;
      *(uint2*)SWZ(Xb, N + (i >> 5), (i & 31) << 3) = z;
    }
    for (int t = tid; t < NP * NP; t += TPB) {
      const int i = t / NP, j = t - i * NP;
      uint8_t v = 0;
      if (i < N && j < N) {
        const float a = adj[i * N + j];
        v = (uint8_t)dist[i * N + j] | (a > 0.f ? 0x80 : 0);
      }
      dm8[t] = v;
    }
    for (int t = tid; t < 120; t += TPB) relL[t] = rel[t];
  }
  __syncthreads();  // b1

  // ---- P2: Q, K, V passes (wave-private transposes; no barriers) -----------
  sh8 qa[3], kb[3];
  {
    f4 acc[3][2];
    gemm_pass(WT, Xb, c, lg, nt0, acc);               // Q
    tr_qk(acc, bq, n0, c, lg, scr, qa);
    gemm_pass(WT + 65536, Xb, c, lg, nt0, acc);       // K
    tr_qk(acc, bk, n0, c, lg, scr, kb);
  }
  f4 av[3][2];
  gemm_pass(WT + 131072, Xb, c, lg, nt0, av);         // V (acc live across b2)
  __syncthreads();  // b2: all Xb reads done before VT overwrites region

  // V epilogue -> VT[d][i] (wave-private rows d in [32w,32w+32))
#pragma unroll
  for (int nt = 0; nt < 2; ++nt) {
    const int n = n0 + 16 * nt + c;
    const float bvv = bv[n];
#pragma unroll
    for (int mt = 0; mt < 3; ++mt) {
      uint2 pk;
      pk.x = cvtpk(av[mt][nt][0] + bvv, av[mt][nt][1] + bvv);
      pk.y = cvtpk(av[mt][nt][2] + bvv, av[mt][nt][3] + bvv);
      *(uint2*)((char*)VT + n * 96 + 32 * mt + 8 * lg) = pk;
    }
  }

  // ---- P3: attention (head h = wave id), S^T = K·Q^T ------------------------
  {
    const int h = w;
    f4 st[3][3];
#pragma unroll
    for (int mt = 0; mt < 3; ++mt)
#pragma unroll
      for (int nt = 0; nt < 3; ++nt) {
        st[mt][nt] = (f4){0.f, 0.f, 0.f, 0.f};
        st[mt][nt] = __builtin_amdgcn_mfma_f32_16x16x32_bf16(kb[mt], qa[nt], st[mt][nt], 0, 0, 0);
      }
    // lane (lg,c) reg r of st[mt][nt]: P-score[i=16nt+c][j=16mt+4lg+r]

    uint16_t* const Psw = scr;  // [48][56] bf16
#pragma unroll
    for (int nt = 0; nt < 3; ++nt) {
      const int i = 16 * nt + c;
      float sv[12];
#pragma unroll
      for (int mt = 0; mt < 3; ++mt)
#pragma unroll
        for (int r = 0; r < 4; ++r) {
          const int j = 16 * mt + 4 * lg + r;
          const uint8_t dm = dm8[i * NP + j];
          const float s = st[mt][nt][r] * SCALE + relL[(dm & 0x7f) * 8 + h];
          sv[mt * 4 + r] = (dm & 0x80) ? s : -1e9f;
        }
      float m = sv[0];
#pragma unroll
      for (int k = 1; k < 12; ++k) m = fmaxf(m, sv[k]);
      m = fmaxf(m, __shfl_xor(m, 16));
      m = fmaxf(m, __shfl_xor(m, 32));
      float p[12], sum = 0.f;
#pragma unroll
      for (int k = 0; k < 12; ++k) { p[k] = __expf(sv[k] - m); sum += p[k]; }
      sum += __shfl_xor(sum, 16);
      sum += __shfl_xor(sum, 32);
      const float inv = __builtin_amdgcn_rcpf(sum);
#pragma unroll
      for (int mt = 0; mt < 3; ++mt) {
        const uint32_t d0 = cvtpk(p[mt * 4 + 0] * inv, p[mt * 4 + 1] * inv);
        const uint32_t d1 = cvtpk(p[mt * 4 + 2] * inv, p[mt * 4 + 3] * inv);
        char* base = (char*)Psw + i * 112 + 32 * mt + 8 * lg;
        *(uint32_t*)base = d0;
        *(uint32_t*)(base + 4) = d1;
      }
    }

    // PV: O_h = P @ V_h (A = P rows from Psw, B = V^T rows from VT)
    const sh8 z8 = {0, 0, 0, 0, 0, 0, 0, 0};
    sh8 pa0[3], pa1[3], vb0[2], vb1[2];
#pragma unroll
    for (int mt = 0; mt < 3; ++mt) {
      char* base = (char*)Psw + (16 * mt + c) * 112;
      pa0[mt] = *(const sh8*)(base + 16 * lg);
      pa1[mt] = (lg < 2) ? *(const sh8*)(base + 64 + 16 * lg) : z8;
    }
#pragma unroll
    for (int nt = 0; nt < 2; ++nt) {
      char* base = (char*)VT + (n0 + 16 * nt + c) * 96;
      vb0[nt] = *(const sh8*)(base + 16 * lg);
      vb1[nt] = (lg < 2) ? *(const sh8*)(base + 64 + 16 * lg) : z8;
    }
    f4 ov[3][2];
#pragma unroll
    for (int mt = 0; mt < 3; ++mt)
#pragma unroll
      for (int nt = 0; nt < 2; ++nt) {
        ov[mt][nt] = (f4){0.f, 0.f, 0.f, 0.f};
        ov[mt][nt] = __builtin_amdgcn_mfma_f32_16x16x32_bf16(pa0[mt], vb0[nt], ov[mt][nt], 0, 0, 0);
        ov[mt][nt] = __builtin_amdgcn_mfma_f32_16x16x32_bf16(pa1[mt], vb1[nt], ov[mt][nt], 0, 0, 0);
      }

    // coalesced attn store from Psw (overlaps other waves' progress)
    const size_t abase = ((size_t)gid * H + h) * (size_t)NN;
    for (int p = lane; p < NN; p += 64) {
      const int i = p / N, j = p - i * N;
      attn[abase + p] = b2f(Psw[i * 56 + j]);
    }
    __syncthreads();  // b5: all VT reads done before O overwrites region

#pragma unroll
    for (int mt = 0; mt < 3; ++mt)
#pragma unroll
      for (int nt = 0; nt < 2; ++nt)
#pragma unroll
        for (int r = 0; r < 4; ++r)
          *(uint16_t*)SWZ(Xb, 16 * mt + 4 * lg + r, (n0 + 16 * nt + c) * 2) =
              f2b1(ov[mt][nt][r]);
  }
  __syncthreads();  // b6

  // ---- P4: out = O @ Wo + bo ------------------------------------------------
  {
    f4 ao[3][2];
    gemm_pass(WT + 196608, Xb, c, lg, nt0, ao);
#pragma unroll
    for (int nt = 0; nt < 2; ++nt) {
      const int n = n0 + 16 * nt + c;
      const float bov = bo[n];
#pragma unroll
      for (int mt = 0; mt < 3; ++mt)
#pragma unroll
        for (int r = 0; r < 4; ++r) {
          const int i = 16 * mt + 4 * lg + r;
          if (i < N) out[(size_t)gid * NE + i * E + n] = ao[mt][nt][r] + bov;
        }
    }
  }
}

extern "C" void kernel_launch(void* const* d_in, const int* in_sizes, int n_in,
                              void* d_out, int out_size, void* d_ws, size_t ws_size,
                              hipStream_t stream) {
  const float* X    = (const float*)d_in[0];
  const float* adj  = (const float*)d_in[1];
  const int*   dist = (const int*)d_in[2];
  const float* Wq   = (const float*)d_in[3];
  const float* bq   = (const float*)d_in[4];
  const float* Wk   = (const float*)d_in[5];
  const float* bk   = (const float*)d_in[6];
  const float* Wv   = (const float*)d_in[7];
  const float* bv   = (const float*)d_in[8];
  const float* Wo   = (const float*)d_in[9];
  const float* bo   = (const float*)d_in[10];
  const float* rel  = (const float*)d_in[11];
  float* out  = (float*)d_out;
  float* attn = out + (size_t)BT * NE;
  uint16_t* WT = (uint16_t*)d_ws;  // 4 * 256*256 bf16 = 512 KB

  wt_kernel<<<dim3(8, 8, 4), dim3(256), 0, stream>>>(Wq, Wk, Wv, Wo, WT);
  gt_kernel<<<dim3(BT), dim3(TPB), 0, stream>>>(
      X, adj, dist, bq, bk, bv, bo, rel, WT, out, attn);
}

// Round 7
// 437.734 us; speedup vs baseline: 1.2239x; 1.2239x over previous
//
#include <hip/hip_runtime.h>
#include <stdint.h>

// GraphTransformerLayer MI355X: B=32 T=128 N=42 E=256 H=8 DH=32, f32 I/O.
// Round 7: round-6 structure + critical fix: P1's pad-row zeroing only covered
// 256 of 512 B per pad row (rows 42-47, cols 128-255 left as LDS garbage).
// Garbage bf16 can decode Inf/NaN -> V rows 42-47 non-finite -> PV MFMA
// 0*Inf=NaN poisons O. Round 5 passed on lucky finite residuals.
// Keeps __launch_bounds__(TPB,2): (TPB,4) forced 64 VGPR -> ~1GB spill traffic.

#define TPB 512
constexpr int BT = 4096;
constexpr int N = 42, NP = 48, E = 256, H = 8;
constexpr int NE = N * E;          // 10752
constexpr int NN = N * N;          // 1764
constexpr float SCALE = 0.17677669529663687f;  // 1/sqrt(32)

typedef short sh8 __attribute__((ext_vector_type(8)));   // 8 bf16
typedef float f4 __attribute__((ext_vector_type(4)));    // MFMA C/D frag

__device__ __forceinline__ uint32_t cvtpk(float lo, float hi) {
  uint32_t d;
  asm("v_cvt_pk_bf16_f32 %0, %1, %2" : "=v"(d) : "v"(lo), "v"(hi));
  return d;
}
__device__ __forceinline__ uint16_t f2b1(float f) { return (uint16_t)cvtpk(f, f); }
__device__ __forceinline__ float b2f(uint16_t u) {
  union { uint32_t i; float f; } v; v.i = ((uint32_t)u) << 16; return v.f;
}

// XOR swizzle for row-major bf16 [*][256] LDS tiles (512B row stride).
#define SWZ(base, row, cb) \
  ((char*)(base) + ((((row) << 9) + (cb)) ^ (((row) & 7) << 4)))

// ---- pre-pass: WT[n][k] = bf16(W[k][n]), 4 matrices -------------------------
__global__ __launch_bounds__(256) void wt_kernel(
    const float* __restrict__ Wq, const float* __restrict__ Wk,
    const float* __restrict__ Wv, const float* __restrict__ Wo,
    uint16_t* __restrict__ WT) {
  __shared__ float tl[32][33];
  const int z = blockIdx.z;
  const float* W = (z == 0) ? Wq : (z == 1) ? Wk : (z == 2) ? Wv : Wo;
  uint16_t* dst = WT + z * 65536;
  const int k0 = blockIdx.y * 32, n0 = blockIdx.x * 32;
  const int r = threadIdx.x >> 5, cc = threadIdx.x & 31;
#pragma unroll
  for (int p = 0; p < 4; ++p)
    tl[r + 8 * p][cc] = W[(k0 + r + 8 * p) * E + n0 + cc];
  __syncthreads();
#pragma unroll
  for (int p = 0; p < 4; ++p)
    dst[(n0 + r + 8 * p) * E + k0 + cc] = f2b1(tl[cc][r + 8 * p]);
}

// one QKV/Wo GEMM pass: acc[mt][nt] += Xb(swz) @ Wt^T tiles
__device__ __forceinline__ void gemm_pass(const uint16_t* __restrict__ Wt,
                                          const char* Xb, int c, int lg, int nt0,
                                          f4 acc[3][2]) {
#pragma unroll
  for (int mt = 0; mt < 3; ++mt)
#pragma unroll
    for (int nt = 0; nt < 2; ++nt) acc[mt][nt] = (f4){0.f, 0.f, 0.f, 0.f};
  for (int kc = 0; kc < E; kc += 32) {
    sh8 xa[3];
#pragma unroll
    for (int mt = 0; mt < 3; ++mt)
      xa[mt] = *(const sh8*)SWZ(Xb, 16 * mt + c, (kc + 8 * lg) * 2);
#pragma unroll
    for (int nt = 0; nt < 2; ++nt) {
      const sh8 b8 = *(const sh8*)(Wt + ((nt0 + nt) * 16 + c) * E + kc + 8 * lg);
#pragma unroll
      for (int mt = 0; mt < 3; ++mt)
        acc[mt][nt] = __builtin_amdgcn_mfma_f32_16x16x32_bf16(xa[mt], b8, acc[mt][nt], 0, 0, 0);
    }
  }
}

// wave-private C-frag -> row-major [48][40] scratch -> A/B frags (lane = row)
__device__ __forceinline__ void tr_qk(const f4 acc[3][2], const float* __restrict__ bias,
                                      int n0, int c, int lg, uint16_t* scr, sh8 fr[3]) {
#pragma unroll
  for (int nt = 0; nt < 2; ++nt) {
    const float bv = bias[n0 + 16 * nt + c];
#pragma unroll
    for (int mt = 0; mt < 3; ++mt)
#pragma unroll
      for (int r = 0; r < 4; ++r)
        scr[(16 * mt + 4 * lg + r) * 40 + 16 * nt + c] = f2b1(acc[mt][nt][r] + bv);
  }
#pragma unroll
  for (int mt = 0; mt < 3; ++mt)
    fr[mt] = *(const sh8*)(scr + (16 * mt + c) * 40 + 8 * lg);
}

// ---- main fused kernel ------------------------------------------------------
// LDS (70368 B -> 2 blocks/CU):
//  [0,24576)      Xb swz [48][256] -> VT [256][48] -> O swz [48][256]
//  [24576,67584)  per-wave 5376B: QK-tr [48][40] -> Ps [48][56]
//  [67584,69888)  dm8 [48][48];  [69888,70368) relL[120]
__global__ __launch_bounds__(TPB, 2) void gt_kernel(
    const float* __restrict__ X, const float* __restrict__ adj,
    const int* __restrict__ dist,
    const float* __restrict__ bq, const float* __restrict__ bk,
    const float* __restrict__ bv, const float* __restrict__ bo,
    const float* __restrict__ rel, const uint16_t* __restrict__ WT,
    float* __restrict__ out, float* __restrict__ attn) {
  alignas(16) __shared__ char smem[70368];
  char* const Xb = smem;
  uint16_t* const VT = (uint16_t*)smem;                 // [256][48]
  uint8_t*  const dm8 = (uint8_t*)(smem + 67584);
  float*    const relL = (float*)(smem + 69888);

  const int gid = blockIdx.x;
  const int tid = threadIdx.x;
  const int w = tid >> 6, lane = tid & 63, c = lane & 15, lg = lane >> 4;
  const int nt0 = 2 * w, n0 = 32 * w;
  uint16_t* const scr = (uint16_t*)(smem + 24576 + w * 5376);  // wave-private

  // ---- P1: stage X (f32->bf16, swizzled) + FULL pad rows + dm8 + rel -------
  {
    const float4* Xs = (const float4*)(X + (size_t)gid * NE);
    for (int i = tid; i < NE / 4; i += TPB) {
      const float4 v = Xs[i];
      uint2 pk; pk.x = cvtpk(v.x, v.y); pk.y = cvtpk(v.z, v.w);
      *(uint2*)SWZ(Xb, i >> 6, (i & 63) << 3) = pk;
    }
    // FIX: zero ALL 512 B of each pad row (64 x 8 B chunks, was 32 -> garbage
    // in cols 128-255 could decode Inf/NaN and poison PV via 0*Inf).
    for (int i = tid; i < (NP - N) * 64; i += TPB) {
      uint2 z; z.x = 0u; z.y = 0u;
      *(uint2*)SWZ(Xb, N + (i >> 6), (i & 63) << 3) = z;
    }
    for (int t = tid; t < NP * NP; t += TPB) {
      const int i = t / NP, j = t - i * NP;
      uint8_t v = 0;
      if (i < N && j < N) {
        const float a = adj[i * N + j];
        v = (uint8_t)dist[i * N + j] | (a > 0.f ? 0x80 : 0);
      }
      dm8[t] = v;
    }
    for (int t = tid; t < 120; t += TPB) relL[t] = rel[t];
  }
  __syncthreads();  // b1

  // ---- P2: Q, K, V passes (wave-private transposes; no barriers) -----------
  sh8 qa[3], kb[3];
  {
    f4 acc[3][2];
    gemm_pass(WT, Xb, c, lg, nt0, acc);               // Q
    tr_qk(acc, bq, n0, c, lg, scr, qa);
    gemm_pass(WT + 65536, Xb, c, lg, nt0, acc);       // K
    tr_qk(acc, bk, n0, c, lg, scr, kb);
  }
  f4 av[3][2];
  gemm_pass(WT + 131072, Xb, c, lg, nt0, av);         // V (acc live across b2)
  __syncthreads();  // b2: all Xb reads done before VT overwrites region

  // V epilogue -> VT[d][i] (wave-private rows d in [32w,32w+32))
#pragma unroll
  for (int nt = 0; nt < 2; ++nt) {
    const int n = n0 + 16 * nt + c;
    const float bvv = bv[n];
#pragma unroll
    for (int mt = 0; mt < 3; ++mt) {
      uint2 pk;
      pk.x = cvtpk(av[mt][nt][0] + bvv, av[mt][nt][1] + bvv);
      pk.y = cvtpk(av[mt][nt][2] + bvv, av[mt][nt][3] + bvv);
      *(uint2*)((char*)VT + n * 96 + 32 * mt + 8 * lg) = pk;
    }
  }

  // ---- P3: attention (head h = wave id), S^T = K·Q^T ------------------------
  {
    const int h = w;
    f4 st[3][3];
#pragma unroll
    for (int mt = 0; mt < 3; ++mt)
#pragma unroll
      for (int nt = 0; nt < 3; ++nt) {
        st[mt][nt] = (f4){0.f, 0.f, 0.f, 0.f};
        st[mt][nt] = __builtin_amdgcn_mfma_f32_16x16x32_bf16(kb[mt], qa[nt], st[mt][nt], 0, 0, 0);
      }
    // lane (lg,c) reg r of st[mt][nt]: P-score[i=16nt+c][j=16mt+4lg+r]

    uint16_t* const Psw = scr;  // [48][56] bf16
#pragma unroll
    for (int nt = 0; nt < 3; ++nt) {
      const int i = 16 * nt + c;
      float sv[12];
#pragma unroll
      for (int mt = 0; mt < 3; ++mt)
#pragma unroll
        for (int r = 0; r < 4; ++r) {
          const int j = 16 * mt + 4 * lg + r;
          const uint8_t dm = dm8[i * NP + j];
          const float s = st[mt][nt][r] * SCALE + relL[(dm & 0x7f) * 8 + h];
          sv[mt * 4 + r] = (dm & 0x80) ? s : -1e9f;
        }
      float m = sv[0];
#pragma unroll
      for (int k = 1; k < 12; ++k) m = fmaxf(m, sv[k]);
      m = fmaxf(m, __shfl_xor(m, 16));
      m = fmaxf(m, __shfl_xor(m, 32));
      float p[12], sum = 0.f;
#pragma unroll
      for (int k = 0; k < 12; ++k) { p[k] = __expf(sv[k] - m); sum += p[k]; }
      sum += __shfl_xor(sum, 16);
      sum += __shfl_xor(sum, 32);
      const float inv = __builtin_amdgcn_rcpf(sum);
#pragma unroll
      for (int mt = 0; mt < 3; ++mt) {
        const uint32_t d0 = cvtpk(p[mt * 4 + 0] * inv, p[mt * 4 + 1] * inv);
        const uint32_t d1 = cvtpk(p[mt * 4 + 2] * inv, p[mt * 4 + 3] * inv);
        char* base = (char*)Psw + i * 112 + 32 * mt + 8 * lg;
        *(uint32_t*)base = d0;
        *(uint32_t*)(base + 4) = d1;
      }
    }

    // PV: O_h = P @ V_h (A = P rows from Psw, B = V^T rows from VT)
    const sh8 z8 = {0, 0, 0, 0, 0, 0, 0, 0};
    sh8 pa0[3], pa1[3], vb0[2], vb1[2];
#pragma unroll
    for (int mt = 0; mt < 3; ++mt) {
      char* base = (char*)Psw + (16 * mt + c) * 112;
      pa0[mt] = *(const sh8*)(base + 16 * lg);
      pa1[mt] = (lg < 2) ? *(const sh8*)(base + 64 + 16 * lg) : z8;
    }
#pragma unroll
    for (int nt = 0; nt < 2; ++nt) {
      char* base = (char*)VT + (n0 + 16 * nt + c) * 96;
      vb0[nt] = *(const sh8*)(base + 16 * lg);
      vb1[nt] = (lg < 2) ? *(const sh8*)(base + 64 + 16 * lg) : z8;
    }
    f4 ov[3][2];
#pragma unroll
    for (int mt = 0; mt < 3; ++mt)
#pragma unroll
      for (int nt = 0; nt < 2; ++nt) {
        ov[mt][nt] = (f4){0.f, 0.f, 0.f, 0.f};
        ov[mt][nt] = __builtin_amdgcn_mfma_f32_16x16x32_bf16(pa0[mt], vb0[nt], ov[mt][nt], 0, 0, 0);
        ov[mt][nt] = __builtin_amdgcn_mfma_f32_16x16x32_bf16(pa1[mt], vb1[nt], ov[mt][nt], 0, 0, 0);
      }

    // coalesced attn store from Psw (overlaps other waves' progress)
    const size_t abase = ((size_t)gid * H + h) * (size_t)NN;
    for (int p = lane; p < NN; p += 64) {
      const int i = p / N, j = p - i * N;
      attn[abase + p] = b2f(Psw[i * 56 + j]);
    }
    __syncthreads();  // b5: all VT reads done before O overwrites region

#pragma unroll
    for (int mt = 0; mt < 3; ++mt)
#pragma unroll
      for (int nt = 0; nt < 2; ++nt)
#pragma unroll
        for (int r = 0; r < 4; ++r)
          *(uint16_t*)SWZ(Xb, 16 * mt + 4 * lg + r, (n0 + 16 * nt + c) * 2) =
              f2b1(ov[mt][nt][r]);
  }
  __syncthreads();  // b6

  // ---- P4: out = O @ Wo + bo ------------------------------------------------
  {
    f4 ao[3][2];
    gemm_pass(WT + 196608, Xb, c, lg, nt0, ao);
#pragma unroll
    for (int nt = 0; nt < 2; ++nt) {
      const int n = n0 + 16 * nt + c;
      const float bov = bo[n];
#pragma unroll
      for (int mt = 0; mt < 3; ++mt)
#pragma unroll
        for (int r = 0; r < 4; ++r) {
          const int i = 16 * mt + 4 * lg + r;
          if (i < N) out[(size_t)gid * NE + i * E + n] = ao[mt][nt][r] + bov;
        }
    }
  }
}

extern "C" void kernel_launch(void* const* d_in, const int* in_sizes, int n_in,
                              void* d_out, int out_size, void* d_ws, size_t ws_size,
                              hipStream_t stream) {
  const float* X    = (const float*)d_in[0];
  const float* adj  = (const float*)d_in[1];
  const int*   dist = (const int*)d_in[2];
  const float* Wq   = (const float*)d_in[3];
  const float* bq   = (const float*)d_in[4];
  const float* Wk   = (const float*)d_in[5];
  const float* bk   = (const float*)d_in[6];
  const float* Wv   = (const float*)d_in[7];
  const float* bv   = (const float*)d_in[8];
  const float* Wo   = (const float*)d_in[9];
  const float* bo   = (const float*)d_in[10];
  const float* rel  = (const float*)d_in[11];
  float* out  = (float*)d_out;
  float* attn = out + (size_t)BT * NE;
  uint16_t* WT = (uint16_t*)d_ws;  // 4 * 256*256 bf16 = 512 KB

  wt_kernel<<<dim3(8, 8, 4), dim3(256), 0, stream>>>(Wq, Wk, Wv, Wo, WT);
  gt_kernel<<<dim3(BT), dim3(TPB), 0, stream>>>(
      X, adj, dist, bq, bk, bv, bo, rel, WT, out, attn);
}